// Round 15
// baseline (550.411 us; speedup 1.0000x reference)
//
#include <hip/hip_runtime.h>
#include <hip/hip_bf16.h>
#include <math.h>

// ---------------- bucketed CSR build ----------------
// bucket = dst >> 8 (256 nodes/bucket). NB = ceil(N/256) <= 512.
// R6: single-pass random 4B scatter caused 16x write amplification -> two-level
// counting sort. R10's smaller chunks REGRESSED (LDS init/flush overhead).
// R12: pass B sorts by 11-bit key (dstlocal*8 + rel) so each node's row is
// RELATION-SORTED -> run-length flushes in the agg loop (per-edge 8-way select
// was ~48 VALU/edge in R10; per-edge LDS atomics were 8.7x worse in R11).

#define CSR_CHUNK 8192

__global__ void k_bhist(const int* __restrict__ dst, int* __restrict__ bcount,
                        int E, int NB) {
    __shared__ int h[512];
    int t = threadIdx.x;
    for (int i = t; i < NB; i += 256) h[i] = 0;
    __syncthreads();
    int e0 = blockIdx.x * CSR_CHUNK;
    int e1 = min(e0 + CSR_CHUNK, E);
    for (int i = e0 + t; i < e1; i += 256) atomicAdd(&h[dst[i] >> 8], 1);
    __syncthreads();
    for (int i = t; i < NB; i += 256) {
        int c = h[i];
        if (c) atomicAdd(&bcount[i], c);
    }
}

__global__ void k_bscan(const int* __restrict__ bcount, int* __restrict__ bstart,
                        int* __restrict__ gcur, int* __restrict__ rowptr,
                        int NB, int N, int E) {
    __shared__ int s[512];
    int t = threadIdx.x;
    int v = (t < NB) ? bcount[t] : 0;
    s[t] = v;
    __syncthreads();
    for (int off = 1; off < 512; off <<= 1) {
        int a = (t >= off) ? s[t - off] : 0;
        __syncthreads();
        s[t] += a;
        __syncthreads();
    }
    int excl = s[t] - v;
    if (t < NB) {
        bstart[t] = excl;
        gcur[t] = excl;
    }
    if (t == 0) {
        bstart[NB] = E;
        rowptr[N] = E;
    }
}

// pass A: scatter packed edges grouped by bucket per block.
// pack: dstlocal(8) << 20 | rel(3) << 17 | src(17)
__global__ void k_bscatter(const int* __restrict__ src, const int* __restrict__ dst,
                           const int* __restrict__ et, int* __restrict__ gcur,
                           unsigned* __restrict__ ebuf, int E, int NB) {
    __shared__ int h[512];
    __shared__ int basearr[512];
    int t = threadIdx.x;
    for (int i = t; i < NB; i += 256) h[i] = 0;
    __syncthreads();
    int e0 = blockIdx.x * CSR_CHUNK;
    int e1 = min(e0 + CSR_CHUNK, E);
    for (int i = e0 + t; i < e1; i += 256) atomicAdd(&h[dst[i] >> 8], 1);
    __syncthreads();
    for (int i = t; i < NB; i += 256) {
        int c = h[i];
        basearr[i] = c ? atomicAdd(&gcur[i], c) : 0;
        h[i] = 0;
    }
    __syncthreads();
    for (int i = e0 + t; i < e1; i += 256) {
        int d = dst[i];
        int b = d >> 8;
        int off = atomicAdd(&h[b], 1);
        ebuf[basearr[b] + off] =
            ((unsigned)(d & 255) << 20) | ((unsigned)et[i] << 17) | (unsigned)src[i];
    }
}

// pass B: one block per bucket. 2048-bin (node,rel) counting sort -> rowptr
// (per node) + csr entries (rel<<17|src) sorted by (node, rel).
__global__ void k_bsort(const unsigned* __restrict__ ebuf, const int* __restrict__ bstart,
                        int* __restrict__ rowptr, int* __restrict__ csr, int N) {
    __shared__ int lh[2048];
    __shared__ int ls[2048];
    __shared__ int ss[256];
    int b = blockIdx.x, t = threadIdx.x;
    int e0 = bstart[b], e1 = bstart[b + 1];
    for (int i = t; i < 2048; i += 256) lh[i] = 0;
    __syncthreads();
    for (int i = e0 + t; i < e1; i += 256) {
        unsigned u = ebuf[i];
        atomicAdd(&lh[(int)(((u >> 20) & 255) * 8 + ((u >> 17) & 7))], 1);
    }
    __syncthreads();
    int loc[8];
    int s = 0;
#pragma unroll
    for (int j = 0; j < 8; j++) {
        loc[j] = s;
        s += lh[t * 8 + j];
    }
    ss[t] = s;
    __syncthreads();
    for (int off = 1; off < 256; off <<= 1) {
        int a = (t >= off) ? ss[t - off] : 0;
        __syncthreads();
        ss[t] += a;
        __syncthreads();
    }
    int excl = ss[t] - s;
#pragma unroll
    for (int j = 0; j < 8; j++) ls[t * 8 + j] = excl + loc[j];
    int node = b * 256 + t;
    if (node < N) rowptr[node] = e0 + excl;
    __syncthreads();
    for (int i = t; i < 2048; i += 256) lh[i] = 0;
    __syncthreads();
    for (int i = e0 + t; i < e1; i += 256) {
        unsigned u = ebuf[i];
        int key = (int)(((u >> 20) & 255) * 8 + ((u >> 17) & 7));
        int off = atomicAdd(&lh[key], 1);
        csr[e0 + ls[key] + off] = (int)(u & 0xFFFFF);
    }
}

// ---------------- weight prep ----------------

// Split-transpose into GEMM-B layout with K = i*8 + r (matches z layout):
// wt[o][i*8+r] = bf16(W[r][i][o]); lo = bf16 residual. K=512 rows total.
__global__ void k_wt2(const float* __restrict__ W, __hip_bfloat16* __restrict__ hi,
                      __hip_bfloat16* __restrict__ lo, int OUT, int total) {
    int t = blockIdx.x * blockDim.x + threadIdx.x;
    if (t < total) {
        int per = 64 * OUT;
        int r = t / per;
        int rem = t % per;
        int i = rem / OUT;
        int o = rem % OUT;
        float v = W[t];
        __hip_bfloat16 h = __float2bfloat16(v);
        __hip_bfloat16 l = __float2bfloat16(v - __bfloat162float(h));
        size_t idx = (size_t)o * 512 + i * 8 + r;
        hi[idx] = h;
        lo[idx] = l;
    }
}

// wq[r*64+i] = sum_o W[r,i,o]*Qv[o]; wk likewise. (fp32, tiny)
__global__ void k_wqk(const float* W, const float* Qv, const float* Kv,
                      float* wq, float* wk, int OUT) {
    int t = blockIdx.x * blockDim.x + threadIdx.x;
    if (t < 8 * 64) {
        int r = t >> 6, i = t & 63;
        const float* wrow = W + ((size_t)r * 64 + i) * OUT;
        float a = 0.f, b = 0.f;
        for (int o = 0; o < OUT; o++) {
            float w = wrow[o];
            a += w * Qv[o];
            b += w * Kv[o];
        }
        wq[t] = a;
        wk[t] = b;
    }
}

// ---------------- q/k projection + bf16 table emit ----------------
__global__ __launch_bounds__(256) void k_qk2(
        const float* __restrict__ xin, const float* __restrict__ wq,
        const float* __restrict__ wk, float* __restrict__ qn,
        float* __restrict__ kn, unsigned short* __restrict__ xbb, int N) {
    __shared__ float xt[64][65];
    __shared__ float swq[8 * 65], swk[8 * 65];
    int t = threadIdx.x;
    int nb0 = blockIdx.x * 64;
    for (int i = t; i < 512; i += 256) {
        int r = i >> 6, c = i & 63;
        swq[r * 65 + c] = wq[i];
        swk[r * 65 + c] = wk[i];
    }
    for (int i = t; i < 1024; i += 256) {
        int ns = i >> 4;   // 16 float4 per row
        int c4 = i & 15;
        int n = nb0 + ns;
        float4 v = {0.f, 0.f, 0.f, 0.f};
        if (n < N) v = ((const float4*)xin)[(size_t)n * 16 + c4];
        xt[ns][c4 * 4 + 0] = v.x;
        xt[ns][c4 * 4 + 1] = v.y;
        xt[ns][c4 * 4 + 2] = v.z;
        xt[ns][c4 * 4 + 3] = v.w;
        if (n < N) {
            __hip_bfloat16 b0 = __float2bfloat16(v.x);
            __hip_bfloat16 b1 = __float2bfloat16(v.y);
            __hip_bfloat16 b2 = __float2bfloat16(v.z);
            __hip_bfloat16 b3 = __float2bfloat16(v.w);
            ushort4 o;
            o.x = *(unsigned short*)&b0;
            o.y = *(unsigned short*)&b1;
            o.z = *(unsigned short*)&b2;
            o.w = *(unsigned short*)&b3;
            *(ushort4*)(xbb + (size_t)n * 64 + c4 * 4) = o;
        }
    }
    __syncthreads();
#pragma unroll
    for (int g = t; g < 512; g += 256) {
        int ns = g >> 3, r = g & 7;
        int n = nb0 + ns;
        if (n < N) {
            float qa = 0.f, ka = 0.f;
#pragma unroll
            for (int i = 0; i < 64; i++) {
                float xv = xt[ns][i];
                qa += xv * swq[r * 65 + i];
                ka += xv * swk[r * 65 + i];
            }
            qn[(size_t)n * 8 + r] = qa;
            kn[(size_t)n * 8 + r] = ka;
        }
    }
}

// ---------------- fused aggregation + transform (R15) ----------------
// R13: 4 nodes serial per wave -> dependency chain exposed 4x (153 us).
// R14: 1024-thr block fixed serialization but occupancy fell 67->53%
// (16-wave workgroups cap at ~1-2 blocks/CU) -> 171 us. Phase-1 throughput
// is proportional to RESIDENT WAVES. R15: block = 512 thr = 8 waves =
// 8 nodes, ONE node per wave. Resources (VGPR 28, LDS 16.6 KB) bind above
// the 32-wave/CU cap -> 4 blocks/CU possible. Phase 2: waves 0..OUT/16-1
// each compute one 16-col tile; zt rows 8-15 zeroed so the M=16 MFMA A-tile
// is valid with only 8 live rows. wid<N guard is wave-uniform -> full exec
// at every cross-lane op (R3/R4).
#define ZSTR 520
template <int OUT, bool RELU>
__global__ __launch_bounds__(512) void k_fused(
        const int* __restrict__ rowptr, const int* __restrict__ csr,
        const float* __restrict__ qn, const float* __restrict__ kn,
        const unsigned short* __restrict__ xb,
        const __hip_bfloat16* __restrict__ wthi,
        const __hip_bfloat16* __restrict__ wtlo,
        const float* __restrict__ bias, float* __restrict__ xout, int N) {
    using v8s = __attribute__((ext_vector_type(8))) short;
    using v4f = __attribute__((ext_vector_type(4))) float;
    __shared__ unsigned short zt[16 * ZSTR];
    int wv = threadIdx.x >> 6;   // 0..7, one node per wave
    int lane = threadIdx.x & 63;
    int nb0 = blockIdx.x * 8;

    // zero the dead upper half of the A-tile (rows 8..15)
    {
        uint4 zz = {0u, 0u, 0u, 0u};
        *(uint4*)&zt[(wv + 8) * ZSTR + lane * 8] = zz;
    }

    // ---- phase 1: aggregate this wave's node into LDS z-tile row wv ----
    int wid = nb0 + wv;
    uint4 pack = {0u, 0u, 0u, 0u};
    if (wid < N) {                 // wave-uniform branch: exec stays full
        int r0 = rowptr[wid], r1 = rowptr[wid + 1];
        float qv = (lane < 8) ? qn[wid * 8 + lane] : 0.f;
        float denom = 0.f;
        float a0 = 0.f, a1 = 0.f, a2 = 0.f, a3 = 0.f;
        float a4 = 0.f, a5 = 0.f, a6 = 0.f, a7 = 0.f;
        int currel = 0;
        float racc = 0.f;

        for (int base = r0; base < r1; base += 64) {
            int s = base + lane;
            int pk = (s < r1) ? csr[s] : 0;
            int src = pk & 0x1FFFF;
            int rel = pk >> 17;
            float qq = __shfl(qv, rel, 64);  // full wave active
            float tv = 0.f;
            if (s < r1) {
                float v = qq + kn[src * 8 + rel];
                v = (v >= 0.f) ? v : 0.2f * v;
                tv = __expf(v);
            }
            float ts = tv;
#pragma unroll
            for (int off = 32; off > 0; off >>= 1) ts += __shfl_xor(ts, off, 64);
            denom += ts;

            int cnt = min(64, r1 - base);
            int tvi = (int)__float_as_uint(tv);
            for (int j = 0; j < cnt; j += 16) {
                unsigned p[16];
                float t[16];
#pragma unroll
                for (int u = 0; u < 16; u++) {
                    p[u] = (unsigned)__builtin_amdgcn_readlane(pk, j + u);
                    t[u] = __uint_as_float(
                        (unsigned)__builtin_amdgcn_readlane(tvi, j + u));
                }
                unsigned xu[16];
#pragma unroll
                for (int u = 0; u < 16; u++)
                    xu[u] = (unsigned)xb[(size_t)(p[u] & 0x1FFFF) * 64 + lane];
#pragma unroll
                for (int u = 0; u < 16; u++) {
                    int rl = (int)(p[u] >> 17);  // SGPR
                    if (rl != currel) {          // uniform scalar branch
                        switch (currel) {
                            case 0: a0 += racc; break;
                            case 1: a1 += racc; break;
                            case 2: a2 += racc; break;
                            case 3: a3 += racc; break;
                            case 4: a4 += racc; break;
                            case 5: a5 += racc; break;
                            case 6: a6 += racc; break;
                            case 7: a7 += racc; break;
                        }
                        currel = rl;
                        racc = 0.f;
                    }
                    racc += t[u] * __uint_as_float(xu[u] << 16);
                }
            }
        }
        switch (currel) {
            case 0: a0 += racc; break;
            case 1: a1 += racc; break;
            case 2: a2 += racc; break;
            case 3: a3 += racc; break;
            case 4: a4 += racc; break;
            case 5: a5 += racc; break;
            case 6: a6 += racc; break;
            case 7: a7 += racc; break;
        }
        float inv = 1.f / (denom + 1e-16f);
        float av[8] = {a0, a1, a2, a3, a4, a5, a6, a7};
        unsigned short u[8];
#pragma unroll
        for (int r = 0; r < 8; r++) {
            __hip_bfloat16 b = __float2bfloat16(av[r] * inv);
            u[r] = *(unsigned short*)&b;
        }
        pack.x = (unsigned)u[0] | ((unsigned)u[1] << 16);
        pack.y = (unsigned)u[2] | ((unsigned)u[3] << 16);
        pack.z = (unsigned)u[4] | ((unsigned)u[5] << 16);
        pack.w = (unsigned)u[6] | ((unsigned)u[7] << 16);
    }
    *(uint4*)&zt[wv * ZSTR + lane * 8] = pack;  // zero for tail rows
    __syncthreads();

    // ---- phase 2: out-tile GEMM from LDS (waves 0..OUT/16-1) ----
    int quad = lane >> 4;
    int l15 = lane & 15;
    int nt = wv;  // 16-col tile per wave
    if (nt * 16 < OUT) {
        const short* wh = (const short*)wthi;
        const short* wl = (const short*)wtlo;
        v4f acc = {0.f, 0.f, 0.f, 0.f};
#pragma unroll
        for (int k0 = 0; k0 < 512; k0 += 32) {
            int koff = k0 + quad * 8;
            v8s A = *(const v8s*)&zt[l15 * ZSTR + koff];
            v8s bh = *(const v8s*)(wh + (size_t)(nt * 16 + l15) * 512 + koff);
            v8s bl = *(const v8s*)(wl + (size_t)(nt * 16 + l15) * 512 + koff);
            acc = __builtin_amdgcn_mfma_f32_16x16x32_bf16(A, bh, acc, 0, 0, 0);
            acc = __builtin_amdgcn_mfma_f32_16x16x32_bf16(A, bl, acc, 0, 0, 0);
        }
        float bcol = bias[nt * 16 + l15];
#pragma unroll
        for (int g = 0; g < 4; g++) {
            int lr = quad * 4 + g;       // local row 0..15; only 0..7 live
            int row = nb0 + lr;
            if (lr < 8 && row < N) {
                float o = acc[g] + bcol;
                if (RELU) o = fmaxf(o, 0.f);
                xout[(size_t)row * OUT + nt * 16 + l15] = o;
            }
        }
    }
}

// ---------------- host launch ----------------

extern "C" void kernel_launch(void* const* d_in, const int* in_sizes, int n_in,
                              void* d_out, int out_size, void* d_ws, size_t ws_size,
                              hipStream_t stream) {
    const float* x   = (const float*)d_in[0];
    const int*   ei  = (const int*)d_in[1];
    const int*   et  = (const int*)d_in[2];
    const float* W0  = (const float*)d_in[3];
    const float* Q0  = (const float*)d_in[4];
    const float* K0  = (const float*)d_in[5];
    const float* b0  = (const float*)d_in[6];
    const float* W1  = (const float*)d_in[7];
    const float* Q1  = (const float*)d_in[8];
    const float* K1  = (const float*)d_in[9];
    const float* b1  = (const float*)d_in[10];
    float* out = (float*)d_out;

    const int N = in_sizes[0] / 64;
    const int E = in_sizes[2];
    const int* src = ei;
    const int* dst = ei + E;
    const int NB = (N + 255) >> 8;  // <= 512

    char* p = (char*)d_ws;
    auto alloc = [&](size_t bytes) -> void* {
        void* r = (void*)p;
        p += ((bytes + 255) / 256) * 256;
        return r;
    };
    int* rowptr   = (int*)alloc((size_t)(N + 1) * 4);
    int* bcount   = (int*)alloc(513 * 4);
    int* bstart   = (int*)alloc(513 * 4);
    int* gcur     = (int*)alloc(513 * 4);
    unsigned* ebuf = (unsigned*)alloc((size_t)E * 4);
    int* csr      = (int*)alloc((size_t)E * 4);
    float* wq     = (float*)alloc(8 * 64 * 4);
    float* wk     = (float*)alloc(8 * 64 * 4);
    float* qn     = (float*)alloc((size_t)N * 8 * 4);
    float* kn     = (float*)alloc((size_t)N * 8 * 4);
    __hip_bfloat16* wthi = (__hip_bfloat16*)alloc((size_t)64 * 512 * 2);
    __hip_bfloat16* wtlo = (__hip_bfloat16*)alloc((size_t)64 * 512 * 2);
    float* h      = (float*)alloc((size_t)N * 64 * 4);
    unsigned short* xbb = (unsigned short*)alloc((size_t)N * 64 * 2);  // bf16 gather table

    // --- CSR build (bucketed counting sort; shared by both layers) ---
    int nchunks = (E + CSR_CHUNK - 1) / CSR_CHUNK;
    hipMemsetAsync(bcount, 0, (size_t)NB * 4, stream);
    k_bhist<<<nchunks, 256, 0, stream>>>(dst, bcount, E, NB);
    k_bscan<<<1, 512, 0, stream>>>(bcount, bstart, gcur, rowptr, NB, N, E);
    k_bscatter<<<nchunks, 256, 0, stream>>>(src, dst, et, gcur, ebuf, E, NB);
    k_bsort<<<NB, 256, 0, stream>>>(ebuf, bstart, rowptr, csr, N);

    int nfb = (N + 7) / 8;
    int nqkb = (N + 63) / 64;

    // --- layer 0: 64 -> 64, relu ---
    k_wqk<<<2, 256, 0, stream>>>(W0, Q0, K0, wq, wk, 64);
    k_qk2<<<nqkb, 256, 0, stream>>>(x, wq, wk, qn, kn, xbb, N);
    k_wt2<<<(8 * 64 * 64 + 255) / 256, 256, 0, stream>>>(W0, wthi, wtlo, 64, 8 * 64 * 64);
    k_fused<64, true><<<nfb, 512, 0, stream>>>(rowptr, csr, qn, kn, xbb,
                                               wthi, wtlo, b0, h, N);

    // --- layer 1: 64 -> 32, no relu ---
    k_wqk<<<2, 256, 0, stream>>>(W1, Q1, K1, wq, wk, 32);
    k_qk2<<<nqkb, 256, 0, stream>>>(h, wq, wk, qn, kn, xbb, N);
    k_wt2<<<(8 * 64 * 32 + 255) / 256, 256, 0, stream>>>(W1, wthi, wtlo, 32, 8 * 64 * 32);
    k_fused<32, false><<<nfb, 512, 0, stream>>>(rowptr, csr, qn, kn, xbb,
                                                wthi, wtlo, b1, out, N);
}

// Round 16
// 546.950 us; speedup vs baseline: 1.0063x; 1.0063x over previous
//
#include <hip/hip_runtime.h>
#include <hip/hip_bf16.h>
#include <math.h>

// ---------------- bucketed CSR build ----------------
// bucket = dst >> 8 (256 nodes/bucket). NB = ceil(N/256) <= 512.
// R6: single-pass random 4B scatter caused 16x write amplification -> two-level
// counting sort. R10's smaller chunks REGRESSED (LDS init/flush overhead).
// R12: pass B sorts by 11-bit key (dstlocal*8 + rel) so each node's row is
// RELATION-SORTED -> run-length flushes in the agg loop (per-edge 8-way select
// was ~48 VALU/edge in R10; per-edge LDS atomics were 8.7x worse in R11).
// R13-R15 fused agg+GEMM variants all landed >= R13's 446 us total (phase-2
// cost scales with block count; barrier couples phases) -> reverted to the
// separate R12 structure with a parallelism-fixed k_zw.

#define CSR_CHUNK 8192

__global__ void k_bhist(const int* __restrict__ dst, int* __restrict__ bcount,
                        int E, int NB) {
    __shared__ int h[512];
    int t = threadIdx.x;
    for (int i = t; i < NB; i += 256) h[i] = 0;
    __syncthreads();
    int e0 = blockIdx.x * CSR_CHUNK;
    int e1 = min(e0 + CSR_CHUNK, E);
    for (int i = e0 + t; i < e1; i += 256) atomicAdd(&h[dst[i] >> 8], 1);
    __syncthreads();
    for (int i = t; i < NB; i += 256) {
        int c = h[i];
        if (c) atomicAdd(&bcount[i], c);
    }
}

__global__ void k_bscan(const int* __restrict__ bcount, int* __restrict__ bstart,
                        int* __restrict__ gcur, int* __restrict__ rowptr,
                        int NB, int N, int E) {
    __shared__ int s[512];
    int t = threadIdx.x;
    int v = (t < NB) ? bcount[t] : 0;
    s[t] = v;
    __syncthreads();
    for (int off = 1; off < 512; off <<= 1) {
        int a = (t >= off) ? s[t - off] : 0;
        __syncthreads();
        s[t] += a;
        __syncthreads();
    }
    int excl = s[t] - v;
    if (t < NB) {
        bstart[t] = excl;
        gcur[t] = excl;
    }
    if (t == 0) {
        bstart[NB] = E;
        rowptr[N] = E;
    }
}

// pass A: scatter packed edges grouped by bucket per block.
// pack: dstlocal(8) << 20 | rel(3) << 17 | src(17)
__global__ void k_bscatter(const int* __restrict__ src, const int* __restrict__ dst,
                           const int* __restrict__ et, int* __restrict__ gcur,
                           unsigned* __restrict__ ebuf, int E, int NB) {
    __shared__ int h[512];
    __shared__ int basearr[512];
    int t = threadIdx.x;
    for (int i = t; i < NB; i += 256) h[i] = 0;
    __syncthreads();
    int e0 = blockIdx.x * CSR_CHUNK;
    int e1 = min(e0 + CSR_CHUNK, E);
    for (int i = e0 + t; i < e1; i += 256) atomicAdd(&h[dst[i] >> 8], 1);
    __syncthreads();
    for (int i = t; i < NB; i += 256) {
        int c = h[i];
        basearr[i] = c ? atomicAdd(&gcur[i], c) : 0;
        h[i] = 0;
    }
    __syncthreads();
    for (int i = e0 + t; i < e1; i += 256) {
        int d = dst[i];
        int b = d >> 8;
        int off = atomicAdd(&h[b], 1);
        ebuf[basearr[b] + off] =
            ((unsigned)(d & 255) << 20) | ((unsigned)et[i] << 17) | (unsigned)src[i];
    }
}

// pass B: one block per bucket. 2048-bin (node,rel) counting sort -> rowptr
// (per node) + csr entries (rel<<17|src) sorted by (node, rel).
__global__ void k_bsort(const unsigned* __restrict__ ebuf, const int* __restrict__ bstart,
                        int* __restrict__ rowptr, int* __restrict__ csr, int N) {
    __shared__ int lh[2048];
    __shared__ int ls[2048];
    __shared__ int ss[256];
    int b = blockIdx.x, t = threadIdx.x;
    int e0 = bstart[b], e1 = bstart[b + 1];
    for (int i = t; i < 2048; i += 256) lh[i] = 0;
    __syncthreads();
    for (int i = e0 + t; i < e1; i += 256) {
        unsigned u = ebuf[i];
        atomicAdd(&lh[(int)(((u >> 20) & 255) * 8 + ((u >> 17) & 7))], 1);
    }
    __syncthreads();
    int loc[8];
    int s = 0;
#pragma unroll
    for (int j = 0; j < 8; j++) {
        loc[j] = s;
        s += lh[t * 8 + j];
    }
    ss[t] = s;
    __syncthreads();
    for (int off = 1; off < 256; off <<= 1) {
        int a = (t >= off) ? ss[t - off] : 0;
        __syncthreads();
        ss[t] += a;
        __syncthreads();
    }
    int excl = ss[t] - s;
#pragma unroll
    for (int j = 0; j < 8; j++) ls[t * 8 + j] = excl + loc[j];
    int node = b * 256 + t;
    if (node < N) rowptr[node] = e0 + excl;
    __syncthreads();
    for (int i = t; i < 2048; i += 256) lh[i] = 0;
    __syncthreads();
    for (int i = e0 + t; i < e1; i += 256) {
        unsigned u = ebuf[i];
        int key = (int)(((u >> 20) & 255) * 8 + ((u >> 17) & 7));
        int off = atomicAdd(&lh[key], 1);
        csr[e0 + ls[key] + off] = (int)(u & 0xFFFFF);
    }
}

// ---------------- weight prep ----------------

// Split-transpose into GEMM-B layout with K = i*8 + r (matches z layout):
// wt[o][i*8+r] = bf16(W[r][i][o]); lo = bf16 residual. K=512 rows total.
__global__ void k_wt2(const float* __restrict__ W, __hip_bfloat16* __restrict__ hi,
                      __hip_bfloat16* __restrict__ lo, int OUT, int total) {
    int t = blockIdx.x * blockDim.x + threadIdx.x;
    if (t < total) {
        int per = 64 * OUT;
        int r = t / per;
        int rem = t % per;
        int i = rem / OUT;
        int o = rem % OUT;
        float v = W[t];
        __hip_bfloat16 h = __float2bfloat16(v);
        __hip_bfloat16 l = __float2bfloat16(v - __bfloat162float(h));
        size_t idx = (size_t)o * 512 + i * 8 + r;
        hi[idx] = h;
        lo[idx] = l;
    }
}

// wq[r*64+i] = sum_o W[r,i,o]*Qv[o]; wk likewise. (fp32, tiny)
__global__ void k_wqk(const float* W, const float* Qv, const float* Kv,
                      float* wq, float* wk, int OUT) {
    int t = blockIdx.x * blockDim.x + threadIdx.x;
    if (t < 8 * 64) {
        int r = t >> 6, i = t & 63;
        const float* wrow = W + ((size_t)r * 64 + i) * OUT;
        float a = 0.f, b = 0.f;
        for (int o = 0; o < OUT; o++) {
            float w = wrow[o];
            a += w * Qv[o];
            b += w * Kv[o];
        }
        wq[t] = a;
        wk[t] = b;
    }
}

// ---------------- q/k projection + bf16 table emit ----------------
__global__ __launch_bounds__(256) void k_qk2(
        const float* __restrict__ xin, const float* __restrict__ wq,
        const float* __restrict__ wk, float* __restrict__ qn,
        float* __restrict__ kn, unsigned short* __restrict__ xbb, int N) {
    __shared__ float xt[64][65];
    __shared__ float swq[8 * 65], swk[8 * 65];
    int t = threadIdx.x;
    int nb0 = blockIdx.x * 64;
    for (int i = t; i < 512; i += 256) {
        int r = i >> 6, c = i & 63;
        swq[r * 65 + c] = wq[i];
        swk[r * 65 + c] = wk[i];
    }
    for (int i = t; i < 1024; i += 256) {
        int ns = i >> 4;   // 16 float4 per row
        int c4 = i & 15;
        int n = nb0 + ns;
        float4 v = {0.f, 0.f, 0.f, 0.f};
        if (n < N) v = ((const float4*)xin)[(size_t)n * 16 + c4];
        xt[ns][c4 * 4 + 0] = v.x;
        xt[ns][c4 * 4 + 1] = v.y;
        xt[ns][c4 * 4 + 2] = v.z;
        xt[ns][c4 * 4 + 3] = v.w;
        if (n < N) {
            __hip_bfloat16 b0 = __float2bfloat16(v.x);
            __hip_bfloat16 b1 = __float2bfloat16(v.y);
            __hip_bfloat16 b2 = __float2bfloat16(v.z);
            __hip_bfloat16 b3 = __float2bfloat16(v.w);
            ushort4 o;
            o.x = *(unsigned short*)&b0;
            o.y = *(unsigned short*)&b1;
            o.z = *(unsigned short*)&b2;
            o.w = *(unsigned short*)&b3;
            *(ushort4*)(xbb + (size_t)n * 64 + c4 * 4) = o;
        }
    }
    __syncthreads();
#pragma unroll
    for (int g = t; g < 512; g += 256) {
        int ns = g >> 3, r = g & 7;
        int n = nb0 + ns;
        if (n < N) {
            float qa = 0.f, ka = 0.f;
#pragma unroll
            for (int i = 0; i < 64; i++) {
                float xv = xt[ns][i];
                qa += xv * swq[r * 65 + i];
                ka += xv * swk[r * 65 + i];
            }
            qn[(size_t)n * 8 + r] = qa;
            kn[(size_t)n * 8 + r] = ka;
        }
    }
}

// ---------------- aggregation into per-relation z (bf16) ----------------
// One wave per dst node. Single-pass softmax (no max-sub; logits O(+-6)).
// Rel-sorted CSR -> run-length accumulation (R12; proven <=82 us).
// HAZARD (R3/R4): all cross-lane ops run with the FULL wave active.
__global__ __launch_bounds__(256) void k_agg4(
        const int* __restrict__ rowptr, const int* __restrict__ csr,
        const float* __restrict__ qn, const float* __restrict__ kn,
        const unsigned short* __restrict__ xb,
        __hip_bfloat16* __restrict__ z, int N) {
    int wid = (blockIdx.x * blockDim.x + threadIdx.x) >> 6;
    int lane = threadIdx.x & 63;
    if (wid >= N) return;
    int r0 = rowptr[wid], r1 = rowptr[wid + 1];

    float qv = (lane < 8) ? qn[wid * 8 + lane] : 0.f;

    float denom = 0.f;
    float a0 = 0.f, a1 = 0.f, a2 = 0.f, a3 = 0.f;
    float a4 = 0.f, a5 = 0.f, a6 = 0.f, a7 = 0.f;
    int currel = 0;      // SGPR (uniform)
    float racc = 0.f;    // current run's accumulator

    for (int base = r0; base < r1; base += 64) {
        int s = base + lane;
        int pk = (s < r1) ? csr[s] : 0;
        int src = pk & 0x1FFFF;
        int rel = pk >> 17;
        float q = __shfl(qv, rel, 64);  // full wave active here
        float tv = 0.f;
        if (s < r1) {
            float v = q + kn[src * 8 + rel];
            v = (v >= 0.f) ? v : 0.2f * v;
            tv = __expf(v);
        }
        float ts = tv;
#pragma unroll
        for (int off = 32; off > 0; off >>= 1) ts += __shfl_xor(ts, off, 64);
        denom += ts;

        int cnt = min(64, r1 - base);
        int tvi = (int)__float_as_uint(tv);
        for (int j = 0; j < cnt; j += 16) {
            // broadcast 16 edges' metadata to SGPRs
            unsigned p[16];
            float t[16];
#pragma unroll
            for (int u = 0; u < 16; u++) {
                p[u] = (unsigned)__builtin_amdgcn_readlane(pk, j + u);
                t[u] = __uint_as_float((unsigned)__builtin_amdgcn_readlane(tvi, j + u));
            }
            // 16 independent gathers, issued back-to-back
            unsigned xu[16];
#pragma unroll
            for (int u = 0; u < 16; u++)
                xu[u] = (unsigned)xb[(size_t)(p[u] & 0x1FFFF) * 64 + lane];
            // run-length accumulate: flush only when (uniform) rel changes
#pragma unroll
            for (int u = 0; u < 16; u++) {
                int rl = (int)(p[u] >> 17);  // SGPR
                if (rl != currel) {          // uniform scalar branch
                    switch (currel) {
                        case 0: a0 += racc; break;
                        case 1: a1 += racc; break;
                        case 2: a2 += racc; break;
                        case 3: a3 += racc; break;
                        case 4: a4 += racc; break;
                        case 5: a5 += racc; break;
                        case 6: a6 += racc; break;
                        case 7: a7 += racc; break;
                    }
                    currel = rl;
                    racc = 0.f;
                }
                racc += t[u] * __uint_as_float(xu[u] << 16);
            }
        }
    }
    // final flush
    switch (currel) {
        case 0: a0 += racc; break;
        case 1: a1 += racc; break;
        case 2: a2 += racc; break;
        case 3: a3 += racc; break;
        case 4: a4 += racc; break;
        case 5: a5 += racc; break;
        case 6: a6 += racc; break;
        case 7: a7 += racc; break;
    }

    float inv = 1.f / (denom + 1e-16f);
    unsigned short u[8];
    float av[8] = {a0, a1, a2, a3, a4, a5, a6, a7};
#pragma unroll
    for (int r = 0; r < 8; r++) {
        __hip_bfloat16 b = __float2bfloat16(av[r] * inv);
        u[r] = *(unsigned short*)&b;
    }
    uint4 pack;
    pack.x = (unsigned)u[0] | ((unsigned)u[1] << 16);
    pack.y = (unsigned)u[2] | ((unsigned)u[3] << 16);
    pack.z = (unsigned)u[4] | ((unsigned)u[5] << 16);
    pack.w = (unsigned)u[6] | ((unsigned)u[7] << 16);
    *(uint4*)((unsigned short*)z + (size_t)wid * 512 + lane * 8) = pack;
}

// ---------------- final transform: out = z . Wcat (+bias, relu) ----------------
// GEMM M=N, K=512, N=OUT via mfma_f32_16x16x32_bf16.
// R16: R12's zw was latency-bound at Occupancy 26% — grid was only 782
// blocks (3/CU) with 32 nodes + all col-tiles serial per wave. Now: wave =
// 16 nodes, A-fragments preloaded ONCE into 64 VGPRs (16 x v8s) and reused
// across col-tiles; K fully unrolled so all loads pipeline. Grid doubles to
// (N+63)/64 blocks -> ~24 waves/CU requested.
template <int OUT, bool RELU>
__global__ __launch_bounds__(256) void k_zw(
        const __hip_bfloat16* __restrict__ z,
        const __hip_bfloat16* __restrict__ wthi, const __hip_bfloat16* __restrict__ wtlo,
        const float* __restrict__ bias, float* __restrict__ xout, int N) {
    using v8s = __attribute__((ext_vector_type(8))) short;
    using v4f = __attribute__((ext_vector_type(4))) float;
    constexpr int NT = OUT / 16;
    int wave = threadIdx.x >> 6;
    int lane = threadIdx.x & 63;
    int quad = lane >> 4;
    int l15 = lane & 15;
    int m0 = (blockIdx.x * 4 + wave) * 16;
    if (m0 >= N) return;

    const short* zp = (const short*)z;
    const short* wh = (const short*)wthi;
    const short* wl = (const short*)wtlo;
    int n0 = m0 + l15;
    bool valid = n0 < N;

    // preload all 16 A-fragments (64 VGPRs), reused across col-tiles
    v8s A[16];
#pragma unroll
    for (int k = 0; k < 16; k++) {
        v8s a = {};
        if (valid) a = *(const v8s*)(zp + (size_t)n0 * 512 + k * 32 + quad * 8);
        A[k] = a;
    }

#pragma unroll
    for (int nt = 0; nt < NT; nt++) {
        const short* bhp = wh + (size_t)(nt * 16 + l15) * 512 + quad * 8;
        const short* blp = wl + (size_t)(nt * 16 + l15) * 512 + quad * 8;
        v4f acc = {0.f, 0.f, 0.f, 0.f};
#pragma unroll
        for (int k = 0; k < 16; k++) {
            v8s bh = *(const v8s*)(bhp + k * 32);
            v8s bl = *(const v8s*)(blp + k * 32);
            acc = __builtin_amdgcn_mfma_f32_16x16x32_bf16(A[k], bh, acc, 0, 0, 0);
            acc = __builtin_amdgcn_mfma_f32_16x16x32_bf16(A[k], bl, acc, 0, 0, 0);
        }
        float bcol = bias[nt * 16 + l15];
#pragma unroll
        for (int g = 0; g < 4; g++) {
            int row = m0 + quad * 4 + g;
            if (row < N) {
                float o = acc[g] + bcol;
                if (RELU) o = fmaxf(o, 0.f);
                xout[(size_t)row * OUT + nt * 16 + l15] = o;
            }
        }
    }
}

// ---------------- host launch ----------------

extern "C" void kernel_launch(void* const* d_in, const int* in_sizes, int n_in,
                              void* d_out, int out_size, void* d_ws, size_t ws_size,
                              hipStream_t stream) {
    const float* x   = (const float*)d_in[0];
    const int*   ei  = (const int*)d_in[1];
    const int*   et  = (const int*)d_in[2];
    const float* W0  = (const float*)d_in[3];
    const float* Q0  = (const float*)d_in[4];
    const float* K0  = (const float*)d_in[5];
    const float* b0  = (const float*)d_in[6];
    const float* W1  = (const float*)d_in[7];
    const float* Q1  = (const float*)d_in[8];
    const float* K1  = (const float*)d_in[9];
    const float* b1  = (const float*)d_in[10];
    float* out = (float*)d_out;

    const int N = in_sizes[0] / 64;
    const int E = in_sizes[2];
    const int* src = ei;
    const int* dst = ei + E;
    const int NB = (N + 255) >> 8;  // <= 512

    char* p = (char*)d_ws;
    auto alloc = [&](size_t bytes) -> void* {
        void* r = (void*)p;
        p += ((bytes + 255) / 256) * 256;
        return r;
    };
    int* rowptr   = (int*)alloc((size_t)(N + 1) * 4);
    int* bcount   = (int*)alloc(513 * 4);
    int* bstart   = (int*)alloc(513 * 4);
    int* gcur     = (int*)alloc(513 * 4);
    unsigned* ebuf = (unsigned*)alloc((size_t)E * 4);
    int* csr      = (int*)alloc((size_t)E * 4);
    float* wq     = (float*)alloc(8 * 64 * 4);
    float* wk     = (float*)alloc(8 * 64 * 4);
    float* qn     = (float*)alloc((size_t)N * 8 * 4);
    float* kn     = (float*)alloc((size_t)N * 8 * 4);
    __hip_bfloat16* wthi = (__hip_bfloat16*)alloc((size_t)64 * 512 * 2);
    __hip_bfloat16* wtlo = (__hip_bfloat16*)alloc((size_t)64 * 512 * 2);
    __hip_bfloat16* z    = (__hip_bfloat16*)alloc((size_t)N * 512 * 2);
    float* h      = (float*)alloc((size_t)N * 64 * 4);
    unsigned short* xbb = (unsigned short*)alloc((size_t)N * 64 * 2);  // bf16 gather table

    // --- CSR build (bucketed counting sort; shared by both layers) ---
    int nchunks = (E + CSR_CHUNK - 1) / CSR_CHUNK;
    hipMemsetAsync(bcount, 0, (size_t)NB * 4, stream);
    k_bhist<<<nchunks, 256, 0, stream>>>(dst, bcount, E, NB);
    k_bscan<<<1, 512, 0, stream>>>(bcount, bstart, gcur, rowptr, NB, N, E);
    k_bscatter<<<nchunks, 256, 0, stream>>>(src, dst, et, gcur, ebuf, E, NB);
    k_bsort<<<NB, 256, 0, stream>>>(ebuf, bstart, rowptr, csr, N);

    int naggb = (N * 64 + 255) / 256;
    int nzwb = (N + 63) / 64;
    int nqkb = (N + 63) / 64;

    // --- layer 0: 64 -> 64, relu ---
    k_wqk<<<2, 256, 0, stream>>>(W0, Q0, K0, wq, wk, 64);
    k_qk2<<<nqkb, 256, 0, stream>>>(x, wq, wk, qn, kn, xbb, N);
    k_wt2<<<(8 * 64 * 64 + 255) / 256, 256, 0, stream>>>(W0, wthi, wtlo, 64, 8 * 64 * 64);
    k_agg4<<<naggb, 256, 0, stream>>>(rowptr, csr, qn, kn, xbb, z, N);
    k_zw<64, true><<<nzwb, 256, 0, stream>>>(z, wthi, wtlo, b0, h, N);

    // --- layer 1: 64 -> 32, no relu ---
    k_wqk<<<2, 256, 0, stream>>>(W1, Q1, K1, wq, wk, 32);
    k_qk2<<<nqkb, 256, 0, stream>>>(h, wq, wk, qn, kn, xbb, N);
    k_wt2<<<(8 * 64 * 32 + 255) / 256, 256, 0, stream>>>(W1, wthi, wtlo, 32, 8 * 64 * 32);
    k_agg4<<<naggb, 256, 0, stream>>>(rowptr, csr, qn, kn, xbb, z, N);
    k_zw<32, false><<<nzwb, 256, 0, stream>>>(z, wthi, wtlo, b1, out, N);
}

// Round 17
// 505.670 us; speedup vs baseline: 1.0885x; 1.0816x over previous
//
#include <hip/hip_runtime.h>
#include <hip/hip_bf16.h>
#include <math.h>

// ---------------- bucketed CSR build (unchanged, proven) ----------------
// R6: two-level counting sort kills scatter write-amplification.
// R12: pass B sorts by (dstlocal*8+rel) -> rel-sorted rows (now also gives
// the xw2-gather same-relation row clustering -> L2 locality).

#define CSR_CHUNK 8192

__global__ void k_bhist(const int* __restrict__ dst, int* __restrict__ bcount,
                        int E, int NB) {
    __shared__ int h[512];
    int t = threadIdx.x;
    for (int i = t; i < NB; i += 256) h[i] = 0;
    __syncthreads();
    int e0 = blockIdx.x * CSR_CHUNK;
    int e1 = min(e0 + CSR_CHUNK, E);
    for (int i = e0 + t; i < e1; i += 256) atomicAdd(&h[dst[i] >> 8], 1);
    __syncthreads();
    for (int i = t; i < NB; i += 256) {
        int c = h[i];
        if (c) atomicAdd(&bcount[i], c);
    }
}

__global__ void k_bscan(const int* __restrict__ bcount, int* __restrict__ bstart,
                        int* __restrict__ gcur, int* __restrict__ rowptr,
                        int NB, int N, int E) {
    __shared__ int s[512];
    int t = threadIdx.x;
    int v = (t < NB) ? bcount[t] : 0;
    s[t] = v;
    __syncthreads();
    for (int off = 1; off < 512; off <<= 1) {
        int a = (t >= off) ? s[t - off] : 0;
        __syncthreads();
        s[t] += a;
        __syncthreads();
    }
    int excl = s[t] - v;
    if (t < NB) {
        bstart[t] = excl;
        gcur[t] = excl;
    }
    if (t == 0) {
        bstart[NB] = E;
        rowptr[N] = E;
    }
}

__global__ void k_bscatter(const int* __restrict__ src, const int* __restrict__ dst,
                           const int* __restrict__ et, int* __restrict__ gcur,
                           unsigned* __restrict__ ebuf, int E, int NB) {
    __shared__ int h[512];
    __shared__ int basearr[512];
    int t = threadIdx.x;
    for (int i = t; i < NB; i += 256) h[i] = 0;
    __syncthreads();
    int e0 = blockIdx.x * CSR_CHUNK;
    int e1 = min(e0 + CSR_CHUNK, E);
    for (int i = e0 + t; i < e1; i += 256) atomicAdd(&h[dst[i] >> 8], 1);
    __syncthreads();
    for (int i = t; i < NB; i += 256) {
        int c = h[i];
        basearr[i] = c ? atomicAdd(&gcur[i], c) : 0;
        h[i] = 0;
    }
    __syncthreads();
    for (int i = e0 + t; i < e1; i += 256) {
        int d = dst[i];
        int b = d >> 8;
        int off = atomicAdd(&h[b], 1);
        ebuf[basearr[b] + off] =
            ((unsigned)(d & 255) << 20) | ((unsigned)et[i] << 17) | (unsigned)src[i];
    }
}

__global__ void k_bsort(const unsigned* __restrict__ ebuf, const int* __restrict__ bstart,
                        int* __restrict__ rowptr, int* __restrict__ csr, int N) {
    __shared__ int lh[2048];
    __shared__ int ls[2048];
    __shared__ int ss[256];
    int b = blockIdx.x, t = threadIdx.x;
    int e0 = bstart[b], e1 = bstart[b + 1];
    for (int i = t; i < 2048; i += 256) lh[i] = 0;
    __syncthreads();
    for (int i = e0 + t; i < e1; i += 256) {
        unsigned u = ebuf[i];
        atomicAdd(&lh[(int)(((u >> 20) & 255) * 8 + ((u >> 17) & 7))], 1);
    }
    __syncthreads();
    int loc[8];
    int s = 0;
#pragma unroll
    for (int j = 0; j < 8; j++) {
        loc[j] = s;
        s += lh[t * 8 + j];
    }
    ss[t] = s;
    __syncthreads();
    for (int off = 1; off < 256; off <<= 1) {
        int a = (t >= off) ? ss[t - off] : 0;
        __syncthreads();
        ss[t] += a;
        __syncthreads();
    }
    int excl = ss[t] - s;
#pragma unroll
    for (int j = 0; j < 8; j++) ls[t * 8 + j] = excl + loc[j];
    int node = b * 256 + t;
    if (node < N) rowptr[node] = e0 + excl;
    __syncthreads();
    for (int i = t; i < 2048; i += 256) lh[i] = 0;
    __syncthreads();
    for (int i = e0 + t; i < e1; i += 256) {
        unsigned u = ebuf[i];
        int key = (int)(((u >> 20) & 255) * 8 + ((u >> 17) & 7));
        int off = atomicAdd(&lh[key], 1);
        csr[e0 + ls[key] + off] = (int)(u & 0xFFFFF);
    }
}

// ---------------- weight prep ----------------

// Split-transpose (R4-proven B layout): Wt[r][o][i] = bf16(W[r][i][o]); lo = residual.
__global__ void k_wt(const float* __restrict__ W, __hip_bfloat16* __restrict__ Wthi,
                     __hip_bfloat16* __restrict__ Wtlo, int OUT, int total) {
    int t = blockIdx.x * blockDim.x + threadIdx.x;
    if (t < total) {
        int per = 64 * OUT;
        int r = t / per;
        int rem = t % per;
        int i = rem / OUT;
        int o = rem % OUT;
        float v = W[t];
        __hip_bfloat16 hi = __float2bfloat16(v);
        __hip_bfloat16 lo = __float2bfloat16(v - __bfloat162float(hi));
        size_t idx = ((size_t)r * OUT + o) * 64 + i;
        Wthi[idx] = hi;
        Wtlo[idx] = lo;
    }
}

// wq[r*64+i] = sum_o W[r,i,o]*Qv[o]; wk likewise. (fp32, tiny)
__global__ void k_wqk(const float* W, const float* Qv, const float* Kv,
                      float* wq, float* wk, int OUT) {
    int t = blockIdx.x * blockDim.x + threadIdx.x;
    if (t < 8 * 64) {
        int r = t >> 6, i = t & 63;
        const float* wrow = W + ((size_t)r * 64 + i) * OUT;
        float a = 0.f, b = 0.f;
        for (int o = 0; o < OUT; o++) {
            float w = wrow[o];
            a += w * Qv[o];
            b += w * Kv[o];
        }
        wq[t] = a;
        wk[t] = b;
    }
}

// ---------------- q/k projection ----------------
__global__ __launch_bounds__(256) void k_qk2(
        const float* __restrict__ xin, const float* __restrict__ wq,
        const float* __restrict__ wk, float* __restrict__ qn,
        float* __restrict__ kn, int N) {
    __shared__ float xt[64][65];
    __shared__ float swq[8 * 65], swk[8 * 65];
    int t = threadIdx.x;
    int nb0 = blockIdx.x * 64;
    for (int i = t; i < 512; i += 256) {
        int r = i >> 6, c = i & 63;
        swq[r * 65 + c] = wq[i];
        swk[r * 65 + c] = wk[i];
    }
    for (int i = t; i < 1024; i += 256) {
        int ns = i >> 4;
        int c4 = i & 15;
        int n = nb0 + ns;
        float4 v = {0.f, 0.f, 0.f, 0.f};
        if (n < N) v = ((const float4*)xin)[(size_t)n * 16 + c4];
        xt[ns][c4 * 4 + 0] = v.x;
        xt[ns][c4 * 4 + 1] = v.y;
        xt[ns][c4 * 4 + 2] = v.z;
        xt[ns][c4 * 4 + 3] = v.w;
    }
    __syncthreads();
#pragma unroll
    for (int g = t; g < 512; g += 256) {
        int ns = g >> 3, r = g & 7;
        int n = nb0 + ns;
        if (n < N) {
            float qa = 0.f, ka = 0.f;
#pragma unroll
            for (int i = 0; i < 64; i++) {
                float xv = xt[ns][i];
                qa += xv * swq[r * 65 + i];
                ka += xv * swk[r * 65 + i];
            }
            qn[(size_t)n * 8 + r] = qa;
            kn[(size_t)n * 8 + r] = ka;
        }
    }
}

// ---------------- MFMA relation transform -> bf16 xw2 table (R17) ----------------
// xw2[r][n][o] = bf16( X[n][:] . W[r][:][o] ), split-bf16 precision (R4-proven
// fragment layouts; verified correct in R5). All 8 relations computed INSIDE
// the block so x-fragments are loaded once (R5's gridDim.y=8 re-read 100 MB).
template <int OUT>
__global__ __launch_bounds__(256) void k_xw_mfma(
        const float* __restrict__ xin,
        const __hip_bfloat16* __restrict__ wthi, const __hip_bfloat16* __restrict__ wtlo,
        __hip_bfloat16* __restrict__ xw, int N) {
    using v8s = __attribute__((ext_vector_type(8))) short;
    using v4f = __attribute__((ext_vector_type(4))) float;
    int wave = threadIdx.x >> 6;
    int lane = threadIdx.x & 63;
    int quad = lane >> 4;
    int l15 = lane & 15;
    int m0 = blockIdx.x * 64 + wave * 16;
    int node = m0 + l15;

    v8s ahi0 = {}, alo0 = {}, ahi1 = {}, alo1 = {};
    if (node < N) {
        const float* xrow = xin + (size_t)node * 64;
#pragma unroll
        for (int j = 0; j < 8; j++) {
            float f0 = xrow[quad * 8 + j];
            __hip_bfloat16 h0 = __float2bfloat16(f0);
            __hip_bfloat16 l0 = __float2bfloat16(f0 - __bfloat162float(h0));
            ahi0[j] = *(short*)&h0;
            alo0[j] = *(short*)&l0;
            float f1 = xrow[32 + quad * 8 + j];
            __hip_bfloat16 h1 = __float2bfloat16(f1);
            __hip_bfloat16 l1 = __float2bfloat16(f1 - __bfloat162float(h1));
            ahi1[j] = *(short*)&h1;
            alo1[j] = *(short*)&l1;
        }
    }
    for (int r = 0; r < 8; r++) {
        const short* whr = (const short*)(wthi + (size_t)r * OUT * 64);
        const short* wlr = (const short*)(wtlo + (size_t)r * OUT * 64);
#pragma unroll
        for (int nt = 0; nt < OUT; nt += 16) {
            const short* wh = whr + (nt + l15) * 64;
            const short* wl = wlr + (nt + l15) * 64;
            v8s bh0 = *(const v8s*)(wh + quad * 8);
            v8s bh1 = *(const v8s*)(wh + 32 + quad * 8);
            v8s bl0 = *(const v8s*)(wl + quad * 8);
            v8s bl1 = *(const v8s*)(wl + 32 + quad * 8);
            v4f acc = {0.f, 0.f, 0.f, 0.f};
            acc = __builtin_amdgcn_mfma_f32_16x16x32_bf16(ahi0, bh0, acc, 0, 0, 0);
            acc = __builtin_amdgcn_mfma_f32_16x16x32_bf16(ahi1, bh1, acc, 0, 0, 0);
            acc = __builtin_amdgcn_mfma_f32_16x16x32_bf16(ahi0, bl0, acc, 0, 0, 0);
            acc = __builtin_amdgcn_mfma_f32_16x16x32_bf16(ahi1, bl1, acc, 0, 0, 0);
            acc = __builtin_amdgcn_mfma_f32_16x16x32_bf16(alo0, bh0, acc, 0, 0, 0);
            acc = __builtin_amdgcn_mfma_f32_16x16x32_bf16(alo1, bh1, acc, 0, 0, 0);
#pragma unroll
            for (int g = 0; g < 4; g++) {
                int nrow = m0 + quad * 4 + g;
                if (nrow < N)
                    xw[((size_t)r * N + nrow) * OUT + nt + l15] = __float2bfloat16(acc[g]);
            }
        }
    }
}

// ---------------- direct aggregation -> output (R17) ----------------
// out[n][o] = (1/denom) * sum_e t_e * xw2[rel_e][src_e][o] + bias[o].
// No z round-trip, no GEMM, no per-edge relation bookkeeping (the switch /
// run-length machinery of R10-R12 is gone entirely — one fmac per edge).
// Batched-16 gathers (R9's MLP fix). Rel-sorted CSR clusters gather rows of
// the same relation -> L2 locality. For OUT=32 lanes 32-63 mirror lanes 0-31
// (identical addresses -> broadcast; they just don't store).
// HAZARD (R3/R4): all cross-lane ops run with the FULL wave active.
template <int OUT, bool RELU>
__global__ __launch_bounds__(256) void k_agg5(
        const int* __restrict__ rowptr, const int* __restrict__ csr,
        const float* __restrict__ qn, const float* __restrict__ kn,
        const __hip_bfloat16* __restrict__ xw, const float* __restrict__ bias,
        float* __restrict__ xout, int N) {
    int wid = (blockIdx.x * blockDim.x + threadIdx.x) >> 6;
    int lane = threadIdx.x & 63;
    if (wid >= N) return;
    int r0 = rowptr[wid], r1 = rowptr[wid + 1];

    float qv = (lane < 8) ? qn[wid * 8 + lane] : 0.f;
    int chan = lane & (OUT - 1);
    const unsigned short* xwp = (const unsigned short*)xw;

    float denom = 0.f;
    float acc = 0.f;

    for (int base = r0; base < r1; base += 64) {
        int s = base + lane;
        int pk = (s < r1) ? csr[s] : 0;
        int src = pk & 0x1FFFF;
        int rel = pk >> 17;
        float q = __shfl(qv, rel, 64);  // full wave active here
        float tv = 0.f;
        if (s < r1) {
            float v = q + kn[src * 8 + rel];
            v = (v >= 0.f) ? v : 0.2f * v;
            tv = __expf(v);
        }
        float ts = tv;
#pragma unroll
        for (int off = 32; off > 0; off >>= 1) ts += __shfl_xor(ts, off, 64);
        denom += ts;

        int cnt = min(64, r1 - base);
        int tvi = (int)__float_as_uint(tv);
        for (int j = 0; j < cnt; j += 16) {
            unsigned p[16];
            float t[16];
#pragma unroll
            for (int u = 0; u < 16; u++) {
                p[u] = (unsigned)__builtin_amdgcn_readlane(pk, j + u);
                t[u] = __uint_as_float((unsigned)__builtin_amdgcn_readlane(tvi, j + u));
            }
            // 16 independent gathers of xw2 rows (tail: row 0, t=0 -> harmless)
            unsigned xu[16];
#pragma unroll
            for (int u = 0; u < 16; u++) {
                int rl = (int)(p[u] >> 17);
                int sr = (int)(p[u] & 0x1FFFF);
                xu[u] = (unsigned)xwp[((size_t)rl * N + sr) * OUT + chan];
            }
#pragma unroll
            for (int u = 0; u < 16; u++)
                acc += t[u] * __uint_as_float(xu[u] << 16);
        }
    }

    if (lane < OUT) {
        float o = acc / (denom + 1e-16f) + bias[lane];
        if (RELU) o = fmaxf(o, 0.f);
        xout[(size_t)wid * OUT + lane] = o;
    }
}

// ---------------- host launch ----------------

extern "C" void kernel_launch(void* const* d_in, const int* in_sizes, int n_in,
                              void* d_out, int out_size, void* d_ws, size_t ws_size,
                              hipStream_t stream) {
    const float* x   = (const float*)d_in[0];
    const int*   ei  = (const int*)d_in[1];
    const int*   et  = (const int*)d_in[2];
    const float* W0  = (const float*)d_in[3];
    const float* Q0  = (const float*)d_in[4];
    const float* K0  = (const float*)d_in[5];
    const float* b0  = (const float*)d_in[6];
    const float* W1  = (const float*)d_in[7];
    const float* Q1  = (const float*)d_in[8];
    const float* K1  = (const float*)d_in[9];
    const float* b1  = (const float*)d_in[10];
    float* out = (float*)d_out;

    const int N = in_sizes[0] / 64;
    const int E = in_sizes[2];
    const int* src = ei;
    const int* dst = ei + E;
    const int NB = (N + 255) >> 8;  // <= 512

    char* p = (char*)d_ws;
    auto alloc = [&](size_t bytes) -> void* {
        void* r = (void*)p;
        p += ((bytes + 255) / 256) * 256;
        return r;
    };
    int* rowptr   = (int*)alloc((size_t)(N + 1) * 4);
    int* bcount   = (int*)alloc(513 * 4);
    int* bstart   = (int*)alloc(513 * 4);
    int* gcur     = (int*)alloc(513 * 4);
    unsigned* ebuf = (unsigned*)alloc((size_t)E * 4);
    int* csr      = (int*)alloc((size_t)E * 4);
    float* wq     = (float*)alloc(8 * 64 * 4);
    float* wk     = (float*)alloc(8 * 64 * 4);
    float* qn     = (float*)alloc((size_t)N * 8 * 4);
    float* kn     = (float*)alloc((size_t)N * 8 * 4);
    __hip_bfloat16* wthi = (__hip_bfloat16*)alloc((size_t)8 * 64 * 64 * 2);
    __hip_bfloat16* wtlo = (__hip_bfloat16*)alloc((size_t)8 * 64 * 64 * 2);
    __hip_bfloat16* xw2  = (__hip_bfloat16*)alloc((size_t)8 * N * 64 * 2);  // 102 MB
    float* h      = (float*)alloc((size_t)N * 64 * 4);

    // --- CSR build (bucketed counting sort; shared by both layers) ---
    int nchunks = (E + CSR_CHUNK - 1) / CSR_CHUNK;
    hipMemsetAsync(bcount, 0, (size_t)NB * 4, stream);
    k_bhist<<<nchunks, 256, 0, stream>>>(dst, bcount, E, NB);
    k_bscan<<<1, 512, 0, stream>>>(bcount, bstart, gcur, rowptr, NB, N, E);
    k_bscatter<<<nchunks, 256, 0, stream>>>(src, dst, et, gcur, ebuf, E, NB);
    k_bsort<<<NB, 256, 0, stream>>>(ebuf, bstart, rowptr, csr, N);

    int naggb = (N * 64 + 255) / 256;
    int nxb = (N + 63) / 64;
    int nqkb = (N + 63) / 64;

    // --- layer 0: 64 -> 64, relu ---
    k_wqk<<<2, 256, 0, stream>>>(W0, Q0, K0, wq, wk, 64);
    k_qk2<<<nqkb, 256, 0, stream>>>(x, wq, wk, qn, kn, N);
    k_wt<<<(8 * 64 * 64 + 255) / 256, 256, 0, stream>>>(W0, wthi, wtlo, 64, 8 * 64 * 64);
    k_xw_mfma<64><<<nxb, 256, 0, stream>>>(x, wthi, wtlo, xw2, N);
    k_agg5<64, true><<<naggb, 256, 0, stream>>>(rowptr, csr, qn, kn, xw2, b0, h, N);

    // --- layer 1: 64 -> 32, no relu ---
    k_wqk<<<2, 256, 0, stream>>>(W1, Q1, K1, wq, wk, 32);
    k_qk2<<<nqkb, 256, 0, stream>>>(h, wq, wk, qn, kn, N);
    k_wt<<<(8 * 64 * 32 + 255) / 256, 256, 0, stream>>>(W1, wthi, wtlo, 32, 8 * 64 * 32);
    k_xw_mfma<32><<<nxb, 256, 0, stream>>>(h, wthi, wtlo, xw2, N);
    k_agg5<32, false><<<naggb, 256, 0, stream>>>(rowptr, csr, qn, kn, xw2, b1, out, N);
}